// Round 1
// baseline (6742.253 us; speedup 1.0000x reference)
//
#include <hip/hip_runtime.h>
#include <hip/hip_bf16.h>
#include <math.h>

#define B_   128
#define L_   256
#define DW_  100
#define DC_  30
#define DIN0 130
#define HD_  200
#define NT_  18
#define SCAN_G 2

__device__ __forceinline__ float sigm_(float x) { return 1.0f / (1.0f + __expf(-x)); }

// ---------------- embedding gather: x[b][l][0:100]=wemb[words], [100:130]=cemb[caps]
__global__ void k_embed(const int* __restrict__ words, const int* __restrict__ caps,
                        const float* __restrict__ wemb, const float* __restrict__ cemb,
                        float* __restrict__ x) {
    int pos = blockIdx.x;                    // 0..B*L-1
    int w = words[pos], c = caps[pos];
    float* xp = x + (size_t)pos * DIN0;
    for (int t = threadIdx.x; t < DIN0; t += blockDim.x) {
        if (t < DW_) xp[t] = wemb[(size_t)w * DW_ + t];
        else         xp[t] = cemb[(size_t)c * DC_ + (t - DW_)];
    }
}

// ---------------- weight prep: transpose (rows,K) -> dst[k][colOff+r], ld=ldDst
__global__ void k_transpose(const float* __restrict__ src, float* __restrict__ dst,
                            int rows, int K, int ldDst, int colOff) {
    int i = blockIdx.x * blockDim.x + threadIdx.x;
    if (i >= rows * K) return;
    int r = i / K, k = i - r * K;
    dst[(size_t)k * ldDst + colOff + r] = src[i];
}

__global__ void k_bias(const float* bi_f, const float* bh_f,
                       const float* bi_b, const float* bh_b, float* bias) {
    int j = blockIdx.x * blockDim.x + threadIdx.x;
    if (j >= 1600) return;
    bias[j] = (j < 800) ? (bi_f[j] + bh_f[j]) : (bi_b[j - 800] + bh_b[j - 800]);
}

__global__ void k_wlog(const float* __restrict__ Wf, const float* __restrict__ bfv,
                       const float* __restrict__ Wb, const float* __restrict__ bbv,
                       float* __restrict__ wlog, float* __restrict__ blog) {
    int i = blockIdx.x * blockDim.x + threadIdx.x;
    if (i < NT_ * 400) {
        int t = i / 400, k = i - t * 400;
        wlog[i] = (k < HD_) ? Wf[t * HD_ + k] : Wb[t * HD_ + (k - HD_)];
    }
    if (i < NT_) blog[i] = bfv[i] + bbv[i];
}

// ---------------- fp32 tiled GEMM: C[M][N] = A[M][K] @ Bm[K][N] + bias[N]
__global__ __launch_bounds__(256) void k_gemm(const float* __restrict__ A,
                                              const float* __restrict__ Bm,
                                              const float* __restrict__ bias,
                                              float* __restrict__ C,
                                              int M, int N, int K) {
    __shared__ float sA[64][17];   // [m][k] +1 pad
    __shared__ float sB[16][65];   // [k][n] +1 pad
    const int tx = threadIdx.x & 15;
    const int ty = threadIdx.x >> 4;
    const int m0 = blockIdx.y * 64;
    const int n0 = blockIdx.x * 64;
    float acc[4][4] = {{0.f}};
    for (int k0 = 0; k0 < K; k0 += 16) {
        {   // stage A: 64x16
            int k = threadIdx.x & 15;
            int m = threadIdx.x >> 4;
            #pragma unroll
            for (int r = 0; r < 4; r++) {
                int mm = m + r * 16;
                int kk = k0 + k;
                sA[mm][k] = (kk < K) ? A[(size_t)(m0 + mm) * K + kk] : 0.f;
            }
            // stage B: 16x64
            int n  = threadIdx.x & 63;
            int kb = threadIdx.x >> 6;
            #pragma unroll
            for (int r = 0; r < 4; r++) {
                int kk2 = kb + r * 4;
                int kg  = k0 + kk2;
                sB[kk2][n] = (kg < K) ? Bm[(size_t)kg * N + n0 + n] : 0.f;
            }
        }
        __syncthreads();
        #pragma unroll
        for (int kk = 0; kk < 16; kk++) {
            float a[4], b[4];
            #pragma unroll
            for (int i = 0; i < 4; i++) a[i] = sA[ty * 4 + i][kk];
            #pragma unroll
            for (int j = 0; j < 4; j++) b[j] = sB[kk][tx * 4 + j];
            #pragma unroll
            for (int i = 0; i < 4; i++)
                #pragma unroll
                for (int j = 0; j < 4; j++) acc[i][j] += a[i] * b[j];
        }
        __syncthreads();
    }
    #pragma unroll
    for (int i = 0; i < 4; i++) {
        int m = m0 + ty * 4 + i;
        #pragma unroll
        for (int j = 0; j < 4; j++) {
            int n = n0 + tx * 4 + j;
            C[(size_t)m * N + n] = acc[i][j] + bias[n];
        }
    }
}

// ---------------- LSTM scan. gih: (B,L,1600) precomputed gates (biases included).
// whhT: (200,1600) transposed recurrent weights (cols: dir*800 + gate_row).
// hout: (B,L,400) — fwd dir writes cols [0,200), bwd [200,400). Masked (*mf) on store.
// One block per (group of SCAN_G batches, dir). 400 threads; thread j computes gate
// cols j and j+400 for each batch in group.
__global__ __launch_bounds__(400) void k_scan(const float* __restrict__ gih,
                                              const float* __restrict__ whhT,
                                              const int* __restrict__ seq_len,
                                              float* __restrict__ hout) {
    const int dir = blockIdx.x & 1;
    const int grp = blockIdx.x >> 1;
    const int b0  = grp * SCAN_G;
    const int j   = threadIdx.x;          // 0..399
    __shared__ float hs[SCAN_G][200];
    __shared__ float gs[SCAN_G][800];
    for (int i = threadIdx.x; i < SCAN_G * 200; i += blockDim.x) (&hs[0][0])[i] = 0.f;
    float cst[SCAN_G];
    int   sl[SCAN_G];
    #pragma unroll
    for (int g = 0; g < SCAN_G; g++) { cst[g] = 0.f; sl[g] = seq_len[b0 + g]; }
    __syncthreads();
    const float* wcol = whhT + dir * 800 + j;
    for (int t = 0; t < L_; t++) {
        int row[SCAN_G];
        #pragma unroll
        for (int g = 0; g < SCAN_G; g++) {
            int tt = (t < sl[g]) ? (sl[g] - 1 - t) : t;   // reversed index (involution)
            row[g] = dir ? tt : t;
        }
        float acc0[SCAN_G], acc1[SCAN_G];
        #pragma unroll
        for (int g = 0; g < SCAN_G; g++) {
            const float* gp = gih + ((size_t)(b0 + g) * L_ + row[g]) * 1600 + dir * 800;
            acc0[g] = gp[j];
            acc1[g] = gp[j + 400];
        }
        #pragma unroll 4
        for (int k = 0; k < HD_; k++) {
            float w0 = wcol[(size_t)k * 1600];
            float w1 = wcol[(size_t)k * 1600 + 400];
            #pragma unroll
            for (int g = 0; g < SCAN_G; g++) {
                float hv = hs[g][k];
                acc0[g] += w0 * hv;
                acc1[g] += w1 * hv;
            }
        }
        #pragma unroll
        for (int g = 0; g < SCAN_G; g++) { gs[g][j] = acc0[g]; gs[g][j + 400] = acc1[g]; }
        __syncthreads();
        if (j < HD_) {
            #pragma unroll
            for (int g = 0; g < SCAN_G; g++) {
                float gi = gs[g][j], gf = gs[g][200 + j], gg = gs[g][400 + j], go = gs[g][600 + j];
                float cn = sigm_(gf) * cst[g] + sigm_(gi) * tanhf(gg);
                cst[g] = cn;
                float hv = sigm_(go) * tanhf(cn);
                hs[g][j] = hv;
                hout[((size_t)(b0 + g) * L_ + row[g]) * 400 + dir * HD_ + j] =
                    (t < sl[g]) ? hv : 0.f;
            }
        }
        __syncthreads();
    }
}

// ---------------- logits: (B*L, 18) = h1(B*L,400) @ wlog^T(18,400) + blog
__global__ __launch_bounds__(256) void k_logits(const float* __restrict__ h1,
                                                const float* __restrict__ wlog,
                                                const float* __restrict__ blog,
                                                float* __restrict__ logits) {
    __shared__ float sh[8][400];
    __shared__ float sw[NT_ * 400];
    int p0 = blockIdx.x * 8;
    for (int i = threadIdx.x; i < 8 * 400; i += 256) sh[i / 400][i % 400] = h1[(size_t)p0 * 400 + i];
    for (int i = threadIdx.x; i < NT_ * 400; i += 256) sw[i] = wlog[i];
    __syncthreads();
    if (threadIdx.x < 8 * NT_) {
        int pi = threadIdx.x / NT_, tg = threadIdx.x % NT_;
        float a = blog[tg];
        #pragma unroll 4
        for (int k = 0; k < 400; k++) a += sh[pi][k] * sw[tg * 400 + k];
        logits[((size_t)(p0 + pi)) * NT_ + tg] = a;
    }
}

// ---------------- CRF NLL per batch row: one wave per b
__global__ __launch_bounds__(64) void k_crf(const float* __restrict__ logits,
                                            const int* __restrict__ target,
                                            const int* __restrict__ seq_len,
                                            const float* __restrict__ trans,
                                            float* __restrict__ out) {
    int b = blockIdx.x, tid = threadIdx.x;
    __shared__ float str[NT_ * NT_];
    __shared__ float alpha[NT_];
    __shared__ float sgold[1];
    for (int i = tid; i < NT_ * NT_; i += 64) str[i] = trans[i];
    int sl = seq_len[b];
    const float* lg = logits + (size_t)b * L_ * NT_;
    const int* tg = target + (size_t)b * L_;
    if (tid < NT_) alpha[tid] = lg[tid];
    // gold score (parallel over t, wave reduce)
    float gacc = 0.f;
    for (int t = tid; t < L_; t += 64) {
        if (t < sl) {
            gacc += lg[t * NT_ + tg[t]];
            if (t >= 1) gacc += trans[tg[t - 1] * NT_ + tg[t]];
        }
    }
    #pragma unroll
    for (int off = 32; off; off >>= 1) gacc += __shfl_down(gacc, off);
    if (tid == 0) sgold[0] = gacc;
    __syncthreads();
    // forward recurrence
    for (int t = 1; t < L_; t++) {
        if (t < sl) {   // uniform per block
            float v = 0.f;
            if (tid < NT_) {
                float m = -1e30f;
                #pragma unroll
                for (int i = 0; i < NT_; i++) m = fmaxf(m, alpha[i] + str[i * NT_ + tid]);
                float s = 0.f;
                #pragma unroll
                for (int i = 0; i < NT_; i++) s += __expf(alpha[i] + str[i * NT_ + tid] - m);
                v = m + __logf(s) + lg[t * NT_ + tid];
            }
            __syncthreads();
            if (tid < NT_) alpha[tid] = v;
            __syncthreads();
        }
    }
    if (tid == 0) {
        float m = -1e30f;
        for (int i = 0; i < NT_; i++) m = fmaxf(m, alpha[i]);
        float s = 0.f;
        for (int i = 0; i < NT_; i++) s += __expf(alpha[i] - m);
        out[b] = (m + __logf(s)) - sgold[0];
    }
}

extern "C" void kernel_launch(void* const* d_in, const int* in_sizes, int n_in,
                              void* d_out, int out_size, void* d_ws, size_t ws_size,
                              hipStream_t stream) {
    const int*   words  = (const int*)d_in[0];
    const int*   caps   = (const int*)d_in[1];
    const int*   seq    = (const int*)d_in[2];
    const int*   target = (const int*)d_in[3];
    const float* wemb   = (const float*)d_in[4];
    const float* cemb   = (const float*)d_in[5];
    const float* Wih0f  = (const float*)d_in[6];
    const float* Whh0f  = (const float*)d_in[7];
    const float* bih0f  = (const float*)d_in[8];
    const float* bhh0f  = (const float*)d_in[9];
    const float* Wih0b  = (const float*)d_in[10];
    const float* Whh0b  = (const float*)d_in[11];
    const float* bih0b  = (const float*)d_in[12];
    const float* bhh0b  = (const float*)d_in[13];
    const float* Wih1f  = (const float*)d_in[14];
    const float* Whh1f  = (const float*)d_in[15];
    const float* bih1f  = (const float*)d_in[16];
    const float* bhh1f  = (const float*)d_in[17];
    const float* Wih1b  = (const float*)d_in[18];
    const float* Whh1b  = (const float*)d_in[19];
    const float* bih1b  = (const float*)d_in[20];
    const float* bhh1b  = (const float*)d_in[21];
    const float* Wf     = (const float*)d_in[22];
    const float* bfv    = (const float*)d_in[23];
    const float* Wb     = (const float*)d_in[24];
    const float* bbv    = (const float*)d_in[25];
    const float* trans  = (const float*)d_in[26];

    float* wsf    = (float*)d_ws;
    float* gates  = wsf;                      // 52,428,800 floats (B*L*1600)
    float* xbuf   = gates  + 52428800;        //  4,259,840 (B*L*130)
    float* h0     = xbuf   + 4259840;         // 13,107,200 (B*L*400)
    float* h1     = xbuf;                     // alias: x and h0 dead when h1 written
    float* logitsb= h0     + 13107200;        //    589,824 (B*L*18)
    float* wihT0  = logitsb + 589824;         //    208,000 (130x1600)
    float* bias0  = wihT0  + 208000;          //      1,600
    float* whhT0  = bias0  + 1600;            //    320,000 (200x1600)
    float* wihT1  = whhT0  + 320000;          //    640,000 (400x1600)
    float* bias1  = wihT1  + 640000;          //      1,600
    float* whhT1  = bias1  + 1600;            //    320,000
    float* wlog   = whhT1  + 320000;          //      7,200 (18x400)
    float* blog   = wlog   + 7200;            //         18

    // --- weight prep
    k_transpose<<<(800 * 130 + 255) / 256, 256, 0, stream>>>(Wih0f, wihT0, 800, 130, 1600, 0);
    k_transpose<<<(800 * 130 + 255) / 256, 256, 0, stream>>>(Wih0b, wihT0, 800, 130, 1600, 800);
    k_transpose<<<(800 * 200 + 255) / 256, 256, 0, stream>>>(Whh0f, whhT0, 800, 200, 1600, 0);
    k_transpose<<<(800 * 200 + 255) / 256, 256, 0, stream>>>(Whh0b, whhT0, 800, 200, 1600, 800);
    k_transpose<<<(800 * 400 + 255) / 256, 256, 0, stream>>>(Wih1f, wihT1, 800, 400, 1600, 0);
    k_transpose<<<(800 * 400 + 255) / 256, 256, 0, stream>>>(Wih1b, wihT1, 800, 400, 1600, 800);
    k_transpose<<<(800 * 200 + 255) / 256, 256, 0, stream>>>(Whh1f, whhT1, 800, 200, 1600, 0);
    k_transpose<<<(800 * 200 + 255) / 256, 256, 0, stream>>>(Whh1b, whhT1, 800, 200, 1600, 800);
    k_bias<<<7, 256, 0, stream>>>(bih0f, bhh0f, bih0b, bhh0b, bias0);
    k_bias<<<7, 256, 0, stream>>>(bih1f, bhh1f, bih1b, bhh1b, bias1);
    k_wlog<<<(NT_ * 400 + 255) / 256, 256, 0, stream>>>(Wf, bfv, Wb, bbv, wlog, blog);

    // --- embeddings
    k_embed<<<B_ * L_, 128, 0, stream>>>(words, caps, wemb, cemb, xbuf);

    // --- layer 0
    k_gemm<<<dim3(1600 / 64, 32768 / 64), 256, 0, stream>>>(xbuf, wihT0, bias0, gates, 32768, 1600, 130);
    k_scan<<<(B_ / SCAN_G) * 2, 400, 0, stream>>>(gates, whhT0, seq, h0);

    // --- layer 1
    k_gemm<<<dim3(1600 / 64, 32768 / 64), 256, 0, stream>>>(h0, wihT1, bias1, gates, 32768, 1600, 400);
    k_scan<<<(B_ / SCAN_G) * 2, 400, 0, stream>>>(gates, whhT1, seq, h1);

    // --- logits + CRF
    k_logits<<<(B_ * L_) / 8, 256, 0, stream>>>(h1, wlog, blog, logitsb);
    k_crf<<<B_, 64, 0, stream>>>(logitsb, target, seq, trans, (float*)d_out);
}

// Round 2
// 4112.903 us; speedup vs baseline: 1.6393x; 1.6393x over previous
//
#include <hip/hip_runtime.h>
#include <math.h>

#define B_   128
#define L_   256
#define DW_  100
#define DC_  30
#define DIN0 130
#define HD_  200
#define NT_  18
#define SG   16    // batches per scan block

typedef _Float16 half8 __attribute__((ext_vector_type(8)));
typedef _Float16 half4 __attribute__((ext_vector_type(4)));
typedef float    f32x4 __attribute__((ext_vector_type(4)));

__device__ __forceinline__ float sigm_(float x) { return 1.0f / (1.0f + __expf(-x)); }
__device__ __forceinline__ float tanh_(float x) {
    float e = __expf(-2.0f * x);
    return (1.0f - e) / (1.0f + e);
}

// ---------------- embedding gather
__global__ void k_embed(const int* __restrict__ words, const int* __restrict__ caps,
                        const float* __restrict__ wemb, const float* __restrict__ cemb,
                        float* __restrict__ x) {
    int pos = blockIdx.x;
    int w = words[pos], c = caps[pos];
    float* xp = x + (size_t)pos * DIN0;
    for (int t = threadIdx.x; t < DIN0; t += blockDim.x) {
        if (t < DW_) xp[t] = wemb[(size_t)w * DW_ + t];
        else         xp[t] = cemb[(size_t)c * DC_ + (t - DW_)];
    }
}

// ---------------- W_ih prep with gate-interleaved column permutation
// src (800, K) row-major, row r = gate*200 + jh  ->  dst[k][colOff + 4*jh + gate]
__global__ void k_perm_ih(const float* __restrict__ src, float* __restrict__ dst,
                          int K, int colOff) {
    int i = blockIdx.x * blockDim.x + threadIdx.x;
    if (i >= 800 * K) return;
    int r = i / K, k = i - r * K;
    int col = ((r % 200) << 2) + (r / 200);
    dst[(size_t)k * 1600 + colOff + col] = src[i];
}

__global__ void k_bias_perm(const float* bi_f, const float* bh_f,
                            const float* bi_b, const float* bh_b, float* bias) {
    int j = blockIdx.x * blockDim.x + threadIdx.x;
    if (j >= 1600) return;
    int dir = j / 800, r = j - dir * 800;
    int col = dir * 800 + ((r % 200) << 2) + (r / 200);
    bias[col] = dir ? (bi_b[r] + bh_b[r]) : (bi_f[r] + bh_f[r]);
}

__global__ void k_wlog(const float* __restrict__ Wf, const float* __restrict__ bfv,
                       const float* __restrict__ Wb, const float* __restrict__ bbv,
                       float* __restrict__ wlog, float* __restrict__ blog) {
    int i = blockIdx.x * blockDim.x + threadIdx.x;
    if (i < NT_ * 400) {
        int t = i / 400, k = i - t * 400;
        wlog[i] = (k < HD_) ? Wf[t * HD_ + k] : Wb[t * HD_ + (k - HD_)];
    }
    if (i < NT_) blog[i] = bfv[i] + bbv[i];
}

// ---------------- fp32 tiled GEMM, fp16 output: C[M][N] = A[M][K] @ Bm[K][N] + bias[N]
__global__ __launch_bounds__(256) void k_gemm(const float* __restrict__ A,
                                              const float* __restrict__ Bm,
                                              const float* __restrict__ bias,
                                              _Float16* __restrict__ C,
                                              int M, int N, int K) {
    __shared__ float sA[64][17];
    __shared__ float sB[16][65];
    const int tx = threadIdx.x & 15;
    const int ty = threadIdx.x >> 4;
    const int m0 = blockIdx.y * 64;
    const int n0 = blockIdx.x * 64;
    float acc[4][4] = {{0.f}};
    for (int k0 = 0; k0 < K; k0 += 16) {
        {
            int k = threadIdx.x & 15;
            int m = threadIdx.x >> 4;
            #pragma unroll
            for (int r = 0; r < 4; r++) {
                int mm = m + r * 16;
                int kk = k0 + k;
                sA[mm][k] = (kk < K) ? A[(size_t)(m0 + mm) * K + kk] : 0.f;
            }
            int n  = threadIdx.x & 63;
            int kb = threadIdx.x >> 6;
            #pragma unroll
            for (int r = 0; r < 4; r++) {
                int kk2 = kb + r * 4;
                int kg  = k0 + kk2;
                sB[kk2][n] = (kg < K) ? Bm[(size_t)kg * N + n0 + n] : 0.f;
            }
        }
        __syncthreads();
        #pragma unroll
        for (int kk = 0; kk < 16; kk++) {
            float a[4], b[4];
            #pragma unroll
            for (int i = 0; i < 4; i++) a[i] = sA[ty * 4 + i][kk];
            #pragma unroll
            for (int j = 0; j < 4; j++) b[j] = sB[kk][tx * 4 + j];
            #pragma unroll
            for (int i = 0; i < 4; i++)
                #pragma unroll
                for (int j = 0; j < 4; j++) acc[i][j] += a[i] * b[j];
        }
        __syncthreads();
    }
    #pragma unroll
    for (int i = 0; i < 4; i++) {
        int m = m0 + ty * 4 + i;
        #pragma unroll
        for (int j = 0; j < 4; j++) {
            int n = n0 + tx * 4 + j;
            C[(size_t)m * N + n] = (_Float16)(acc[i][j] + bias[n]);
        }
    }
}

// ---------------- MFMA persistent LSTM scan
// gates: (B, L, 1600) fp16, columns = dir*800 + 4*hidden + gate (i,f,g,o)
// Whh_f/Whh_b: raw (800, 200) fp32, row = gate*200 + hidden
// hout: (B, L, 400) fp32; dir0 -> cols [0,200), dir1 -> cols [200,400), masked
// One block per (16-batch group, dir): 8 waves, M=16, N=800 (50 tiles), K=200 (7 K-tiles, padded 224)
__global__ __launch_bounds__(512, 2) void k_scan_mfma(const _Float16* __restrict__ gates,
                                                      const float* __restrict__ Whh_f,
                                                      const float* __restrict__ Whh_b,
                                                      const int* __restrict__ seq_len,
                                                      float* __restrict__ hout) {
    const int dir = blockIdx.x & 1;
    const int b0  = (blockIdx.x >> 1) * SG;
    const int tid = threadIdx.x;
    const int w   = tid >> 6;
    const int l   = tid & 63;
    const int l15 = l & 15;
    const int lq  = l >> 4;

    __shared__ __align__(16) _Float16 hA[16 * 232];        // h state, [m*232 + k], pad->2-way
    __shared__ __align__(16) float    gb[800 * 20];        // gate buf [n*20 + m], pad->2-way
    __shared__ __align__(16) _Float16 bEx[2 * 7 * 512];    // B-frags for tiles 48,49

    const float* W = dir ? Whh_b : Whh_f;

    // ---- build resident B-fragments (6 reg tiles/wave + 2 LDS tiles)
    half8 Breg[6][7];
    #pragma unroll
    for (int i = 0; i < 6; i++) {
        int n  = (w * 6 + i) * 16 + l15;
        int jh = n >> 2, g = n & 3;
        const float* Wr = W + (size_t)(g * 200 + jh) * 200;
        #pragma unroll
        for (int kt = 0; kt < 7; kt++) {
            int k0 = kt * 32 + lq * 8;
            half8 f;
            #pragma unroll
            for (int j = 0; j < 8; j++) {
                int k = k0 + j;
                f[j] = (k < 200) ? (_Float16)Wr[k] : (_Float16)0.f;
            }
            Breg[i][kt] = f;
        }
    }
    if (w < 2) {
        int n  = (48 + w) * 16 + l15;
        int jh = n >> 2, g = n & 3;
        const float* Wr = W + (size_t)(g * 200 + jh) * 200;
        for (int kt = 0; kt < 7; kt++) {
            int k0 = kt * 32 + lq * 8;
            half8 f;
            for (int j = 0; j < 8; j++) {
                int k = k0 + j;
                f[j] = (k < 200) ? (_Float16)Wr[k] : (_Float16)0.f;
            }
            *(half8*)&bEx[(w * 7 + kt) * 512 + l * 8] = f;
        }
    }
    for (int i = tid; i < 16 * 232; i += 512) hA[i] = (_Float16)0.f;

    // nonlinearity work items: thread owns (jA, mq) and (jA+128, mq)
    const int mq = tid & 3;
    const int jA = tid >> 2;        // 0..127
    const int jB = jA + 128;        // valid if < 200
    int slv[4];
    #pragma unroll
    for (int r = 0; r < 4; r++) slv[r] = seq_len[b0 + 4 * mq + r];
    float c0[4] = {0.f, 0.f, 0.f, 0.f};
    float c1[4] = {0.f, 0.f, 0.f, 0.f};
    __syncthreads();

    const f32x4 Cz = {0.f, 0.f, 0.f, 0.f};
    for (int t = 0; t < L_; t++) {
        // ---- MFMA phase: gatesum = h(t-1) @ W^T
        f32x4 C[6], Cx;
        #pragma unroll
        for (int i = 0; i < 6; i++) C[i] = Cz;
        Cx = Cz;
        #pragma unroll
        for (int kt = 0; kt < 7; kt++) {
            half8 aF = *(const half8*)&hA[l15 * 232 + kt * 32 + lq * 8];
            #pragma unroll
            for (int i = 0; i < 6; i++)
                C[i] = __builtin_amdgcn_mfma_f32_16x16x32_f16(aF, Breg[i][kt], C[i], 0, 0, 0);
            if (w < 2) {
                half8 bF = *(const half8*)&bEx[(w * 7 + kt) * 512 + l * 8];
                Cx = __builtin_amdgcn_mfma_f32_16x16x32_f16(aF, bF, Cx, 0, 0, 0);
            }
        }
        #pragma unroll
        for (int i = 0; i < 6; i++) {
            int n = (w * 6 + i) * 16 + l15;
            *(f32x4*)&gb[n * 20 + lq * 4] = C[i];
        }
        if (w < 2) {
            int n = (48 + w) * 16 + l15;
            *(f32x4*)&gb[n * 20 + lq * 4] = Cx;
        }

        // issue gih loads before the barrier so they overlap the drain
        half4 giA[4], giB[4];
        int rowm[4];
        #pragma unroll
        for (int r = 0; r < 4; r++) {
            int sl = slv[r];
            int rt = dir ? ((t < sl) ? (sl - 1 - t) : t) : t;
            rowm[r] = rt;
            const _Float16* gp = gates + ((size_t)(b0 + 4 * mq + r) * L_ + rt) * 1600 + dir * 800;
            giA[r] = *(const half4*)(gp + 4 * jA);
            giB[r] = (jB < 200) ? *(const half4*)(gp + 4 * jB) : half4{};
        }
        __syncthreads();

        // ---- nonlinearity phase
        {
            f32x4 vi = *(const f32x4*)&gb[(4 * jA + 0) * 20 + 4 * mq];
            f32x4 vf = *(const f32x4*)&gb[(4 * jA + 1) * 20 + 4 * mq];
            f32x4 vg = *(const f32x4*)&gb[(4 * jA + 2) * 20 + 4 * mq];
            f32x4 vo = *(const f32x4*)&gb[(4 * jA + 3) * 20 + 4 * mq];
            #pragma unroll
            for (int r = 0; r < 4; r++) {
                float gi = vi[r] + (float)giA[r][0];
                float gf = vf[r] + (float)giA[r][1];
                float gg = vg[r] + (float)giA[r][2];
                float go = vo[r] + (float)giA[r][3];
                float cn = sigm_(gf) * c0[r] + sigm_(gi) * tanh_(gg);
                c0[r] = cn;
                float hv = sigm_(go) * tanh_(cn);
                int m = 4 * mq + r;
                hA[m * 232 + jA] = (_Float16)hv;
                hout[((size_t)(b0 + m) * L_ + rowm[r]) * 400 + dir * HD_ + jA] =
                    (t < slv[r]) ? hv : 0.f;
            }
        }
        if (jB < 200) {
            f32x4 vi = *(const f32x4*)&gb[(4 * jB + 0) * 20 + 4 * mq];
            f32x4 vf = *(const f32x4*)&gb[(4 * jB + 1) * 20 + 4 * mq];
            f32x4 vg = *(const f32x4*)&gb[(4 * jB + 2) * 20 + 4 * mq];
            f32x4 vo = *(const f32x4*)&gb[(4 * jB + 3) * 20 + 4 * mq];
            #pragma unroll
            for (int r = 0; r < 4; r++) {
                float gi = vi[r] + (float)giB[r][0];
                float gf = vf[r] + (float)giB[r][1];
                float gg = vg[r] + (float)giB[r][2];
                float go = vo[r] + (float)giB[r][3];
                float cn = sigm_(gf) * c1[r] + sigm_(gi) * tanh_(gg);
                c1[r] = cn;
                float hv = sigm_(go) * tanh_(cn);
                int m = 4 * mq + r;
                hA[m * 232 + jB] = (_Float16)hv;
                hout[((size_t)(b0 + m) * L_ + rowm[r]) * 400 + dir * HD_ + jB] =
                    (t < slv[r]) ? hv : 0.f;
            }
        }
        __syncthreads();
    }
}

// ---------------- logits: (B*L, 18) = h1(B*L,400) @ wlog^T(18,400) + blog
__global__ __launch_bounds__(256) void k_logits(const float* __restrict__ h1,
                                                const float* __restrict__ wlog,
                                                const float* __restrict__ blog,
                                                float* __restrict__ logits) {
    __shared__ float sh[8][400];
    __shared__ float sw[NT_ * 400];
    int p0 = blockIdx.x * 8;
    for (int i = threadIdx.x; i < 8 * 400; i += 256) sh[i / 400][i % 400] = h1[(size_t)p0 * 400 + i];
    for (int i = threadIdx.x; i < NT_ * 400; i += 256) sw[i] = wlog[i];
    __syncthreads();
    if (threadIdx.x < 8 * NT_) {
        int pi = threadIdx.x / NT_, tg = threadIdx.x % NT_;
        float a = blog[tg];
        #pragma unroll 4
        for (int k = 0; k < 400; k++) a += sh[pi][k] * sw[tg * 400 + k];
        logits[((size_t)(p0 + pi)) * NT_ + tg] = a;
    }
}

// ---------------- CRF NLL per batch row
__global__ __launch_bounds__(64) void k_crf(const float* __restrict__ logits,
                                            const int* __restrict__ target,
                                            const int* __restrict__ seq_len,
                                            const float* __restrict__ trans,
                                            float* __restrict__ out) {
    int b = blockIdx.x, tid = threadIdx.x;
    __shared__ float str[NT_ * NT_];
    __shared__ float alpha[NT_];
    __shared__ float sgold[1];
    for (int i = tid; i < NT_ * NT_; i += 64) str[i] = trans[i];
    int sl = seq_len[b];
    const float* lg = logits + (size_t)b * L_ * NT_;
    const int* tg = target + (size_t)b * L_;
    if (tid < NT_) alpha[tid] = lg[tid];
    float gacc = 0.f;
    for (int t = tid; t < L_; t += 64) {
        if (t < sl) {
            gacc += lg[t * NT_ + tg[t]];
            if (t >= 1) gacc += trans[tg[t - 1] * NT_ + tg[t]];
        }
    }
    #pragma unroll
    for (int off = 32; off; off >>= 1) gacc += __shfl_down(gacc, off);
    if (tid == 0) sgold[0] = gacc;
    __syncthreads();
    for (int t = 1; t < L_; t++) {
        if (t < sl) {
            float v = 0.f;
            if (tid < NT_) {
                float m = -1e30f;
                #pragma unroll
                for (int i = 0; i < NT_; i++) m = fmaxf(m, alpha[i] + str[i * NT_ + tid]);
                float s = 0.f;
                #pragma unroll
                for (int i = 0; i < NT_; i++) s += __expf(alpha[i] + str[i * NT_ + tid] - m);
                v = m + __logf(s) + lg[t * NT_ + tid];
            }
            __syncthreads();
            if (tid < NT_) alpha[tid] = v;
            __syncthreads();
        }
    }
    if (tid == 0) {
        float m = -1e30f;
        for (int i = 0; i < NT_; i++) m = fmaxf(m, alpha[i]);
        float s = 0.f;
        for (int i = 0; i < NT_; i++) s += __expf(alpha[i] - m);
        out[b] = (m + __logf(s)) - sgold[0];
    }
}

extern "C" void kernel_launch(void* const* d_in, const int* in_sizes, int n_in,
                              void* d_out, int out_size, void* d_ws, size_t ws_size,
                              hipStream_t stream) {
    const int*   words  = (const int*)d_in[0];
    const int*   caps   = (const int*)d_in[1];
    const int*   seq    = (const int*)d_in[2];
    const int*   target = (const int*)d_in[3];
    const float* wemb   = (const float*)d_in[4];
    const float* cemb   = (const float*)d_in[5];
    const float* Wih0f  = (const float*)d_in[6];
    const float* Whh0f  = (const float*)d_in[7];
    const float* bih0f  = (const float*)d_in[8];
    const float* bhh0f  = (const float*)d_in[9];
    const float* Wih0b  = (const float*)d_in[10];
    const float* Whh0b  = (const float*)d_in[11];
    const float* bih0b  = (const float*)d_in[12];
    const float* bhh0b  = (const float*)d_in[13];
    const float* Wih1f  = (const float*)d_in[14];
    const float* Whh1f  = (const float*)d_in[15];
    const float* bih1f  = (const float*)d_in[16];
    const float* bhh1f  = (const float*)d_in[17];
    const float* Wih1b  = (const float*)d_in[18];
    const float* Whh1b  = (const float*)d_in[19];
    const float* bih1b  = (const float*)d_in[20];
    const float* bhh1b  = (const float*)d_in[21];
    const float* Wf     = (const float*)d_in[22];
    const float* bfv    = (const float*)d_in[23];
    const float* Wb     = (const float*)d_in[24];
    const float* bbv    = (const float*)d_in[25];
    const float* trans  = (const float*)d_in[26];

    char* base = (char*)d_ws;
    _Float16* gatesH = (_Float16*)base;                            // 104,857,600 B
    float* xbuf    = (float*)(base + 104857600);                   // 17,039,360 B
    float* h0      = (float*)(base + 104857600 + 17039360);        // 52,428,800 B
    float* h1      = xbuf;   // spans xbuf+h0 region (both dead by then)
    float* logitsb = (float*)(base + 174325760);                   // 2,359,296 B
    float* wihT0   = (float*)(base + 176685056);                   // 832,000 B
    float* bias0   = (float*)(base + 177517056);                   // 6,400 B
    float* wihT1   = (float*)(base + 177523456);                   // 2,560,000 B
    float* bias1   = (float*)(base + 180083456);                   // 6,400 B
    float* wlog    = (float*)(base + 180089856);                   // 28,800 B
    float* blog    = (float*)(base + 180118656);                   // 128 B

    // --- weight prep (gate-interleaved columns)
    k_perm_ih<<<(800 * 130 + 255) / 256, 256, 0, stream>>>(Wih0f, wihT0, 130, 0);
    k_perm_ih<<<(800 * 130 + 255) / 256, 256, 0, stream>>>(Wih0b, wihT0, 130, 800);
    k_perm_ih<<<(800 * 400 + 255) / 256, 256, 0, stream>>>(Wih1f, wihT1, 400, 0);
    k_perm_ih<<<(800 * 400 + 255) / 256, 256, 0, stream>>>(Wih1b, wihT1, 400, 800);
    k_bias_perm<<<7, 256, 0, stream>>>(bih0f, bhh0f, bih0b, bhh0b, bias0);
    k_bias_perm<<<7, 256, 0, stream>>>(bih1f, bhh1f, bih1b, bhh1b, bias1);
    k_wlog<<<(NT_ * 400 + 255) / 256, 256, 0, stream>>>(Wf, bfv, Wb, bbv, wlog, blog);

    // --- embeddings
    k_embed<<<B_ * L_, 128, 0, stream>>>(words, caps, wemb, cemb, xbuf);

    // --- layer 0
    k_gemm<<<dim3(1600 / 64, 32768 / 64), 256, 0, stream>>>(xbuf, wihT0, bias0, gatesH, 32768, 1600, 130);
    k_scan_mfma<<<(B_ / SG) * 2, 512, 0, stream>>>(gatesH, Whh0f, Whh0b, seq, h0);

    // --- layer 1
    k_gemm<<<dim3(1600 / 64, 32768 / 64), 256, 0, stream>>>(h0, wihT1, bias1, gatesH, 32768, 1600, 400);
    k_scan_mfma<<<(B_ / SG) * 2, 512, 0, stream>>>(gatesH, Whh1f, Whh1b, seq, h1);

    // --- logits + CRF
    k_logits<<<(B_ * L_) / 8, 256, 0, stream>>>(h1, wlog, blog, logitsb);
    k_crf<<<B_, 64, 0, stream>>>(logitsb, target, seq, trans, (float*)d_out);
}